// Round 5
// baseline (295.430 us; speedup 1.0000x reference)
//
#include <hip/hip_runtime.h>
#include <hip/hip_bf16.h>

#define DEVINL __device__ __forceinline__

constexpr int Bb = 8;
constexpr int Nn = 10000;
constexpr int Ff = 256;     // F (K dim of GEMM)
constexpr int Hh = 128;     // H (N dim of GEMM)
constexpr int Ee = 320000;
constexpr int Mm = Bb * Nn; // 80000 GEMM rows

constexpr int CHUNK = 64;                     // rows per bucket
constexpr int NCH = (Nn + CHUNK - 1) / CHUNK; // 157 buckets/batch
constexpr int CAP = 2560;                     // bucket capacity (mean 2048, 11 sigma)
constexpr int GPB = 80;                       // binning workgroups per batch
constexpr int EPG = Ee / GPB;                 // 4000 edges per workgroup (32 KB LDS)
constexpr int TW_BLOCKS = (Ff * Hh) / 256;    // 128 fragment-pack blocks (fused)

typedef __attribute__((ext_vector_type(8))) short short8;
typedef __attribute__((ext_vector_type(4))) float float4v;
typedef __attribute__((ext_vector_type(4))) unsigned short ushort4v;

DEVINL unsigned short f2b(float f) {
    unsigned int u;
    __builtin_memcpy(&u, &f, 4);
    unsigned int r = (u + 0x7fffu + ((u >> 16) & 1u)) >> 16;
    return (unsigned short)r;
}
DEVINL float i2f(int i) {
    float f;
    __builtin_memcpy(&f, &i, 4);
    return f;
}
DEVINL float lo_bf(unsigned int two) {
    unsigned int u = two << 16;
    float f;
    __builtin_memcpy(&f, &u, 4);
    return f;
}
DEVINL float hi_bf(unsigned int two) {
    unsigned int u = two & 0xffff0000u;
    float f;
    __builtin_memcpy(&f, &u, 4);
    return f;
}

// ---------------- K1: LDS-staged bucket sort (+ fused W fragment pack) -------
// Binning blocks: stage 4000 edges -> LDS histogram over 157 buckets -> scan
// -> LDS bucket-sort -> write each bucket's run CONTIGUOUSLY (mean 200 B/run).
// XCD-swizzled: b = raw&7 -> batch b's cur/bkt stay on XCD b's L2.
// Pack blocks: w[K][H] fp32 -> wF in MFMA-B-fragment order:
//   wF[ksl*4096 + tt*512 + lane*8 + j] = bf16(w[(ksl*32 + (lane>>4)*8 + j)*H
//                                               + tt*16 + (lane&15)])
// so gemm's B-fragment load is a single coalesced 1 KB wave-read (imm offsets).
__global__ __launch_bounds__(256) void bucket2_kernel(const int* __restrict__ rows,
                                                      const int* __restrict__ cols,
                                                      const float* __restrict__ vals,
                                                      int* __restrict__ cur,
                                                      int2* __restrict__ bkt,
                                                      const float* __restrict__ w,
                                                      unsigned short* __restrict__ wF) {
    int t = threadIdx.x;
    if (blockIdx.x >= Bb * GPB) {
        int idx = (blockIdx.x - Bb * GPB) * 256 + t;
        if (idx < Ff * Hh) {
            int j = idx & 7;
            int lane = (idx >> 3) & 63;
            int tt = (idx >> 9) & 7;
            int ksl = idx >> 12;
            int k = ksl * 32 + (lane >> 4) * 8 + j;
            int h = tt * 16 + (lane & 15);
            wF[idx] = f2b(w[(size_t)k * Hh + h]);
        }
        return;
    }
    __shared__ int2 sedge[EPG];            // 32 KB sorted edges
    __shared__ int lcnt[NCH];
    __shared__ int lofs[NCH];
    __shared__ int lcur[NCH];
    __shared__ int gall[NCH];
    __shared__ int wsum[4];
    int raw = blockIdx.x;
    int b = raw & 7;
    int g = raw >> 3;
    const int base = b * Ee + g * EPG;

    for (int j = t; j < NCH; j += 256) lcnt[j] = 0;
    __syncthreads();
    for (int i = t; i < EPG; i += 256)
        atomicAdd(&lcnt[rows[base + i] >> 6], 1);
    __syncthreads();
    // exclusive scan over 157 buckets (256-thread, one pass)
    {
        int lane = t & 63, wv = t >> 6;
        int v = (t < NCH) ? lcnt[t] : 0;
        int incl = v;
#pragma unroll
        for (int d = 1; d < 64; d <<= 1) {
            int o = __shfl_up(incl, d);
            if (lane >= d) incl += o;
        }
        if (lane == 63) wsum[wv] = incl;
        __syncthreads();
        if (t == 0) {
            int s = 0;
#pragma unroll
            for (int k = 0; k < 4; k++) { int x = wsum[k]; wsum[k] = s; s += x; }
        }
        __syncthreads();
        if (t < NCH) {
            int ex = incl - v + wsum[wv];
            lofs[t] = ex;
            lcur[t] = ex;
        }
    }
    __syncthreads();
    // reserve global bucket space; gall[j] = gbase - lofs[j] so slot = gall[j]+i
    for (int j = t; j < NCH; j += 256) {
        int gb = atomicAdd(&cur[b * NCH + j], lcnt[j]);
        gall[j] = gb - lofs[j];
    }
    __syncthreads();
    // bucket-sort edges into LDS
    for (int i = t; i < EPG; i += 256) {
        int r = rows[base + i];
        int c = cols[base + i];
        float vf = vals[base + i];
        int vb;
        __builtin_memcpy(&vb, &vf, 4);
        int bk = r >> 6;
        int p = atomicAdd(&lcur[bk], 1);
        sedge[p] = make_int2(((r & 63) << 26) | (c << 8) | bk, vb);
    }
    __syncthreads();
    // contiguous run writes
    for (int i = t; i < EPG; i += 256) {
        int2 e = sedge[i];
        int j = e.x & 0xff;
        int slot = gall[j] + i;
        if (slot < CAP)
            bkt[(size_t)(b * NCH + j) * CAP + slot] = e;
    }
}

// ---------------- fused dropout + GEMM (staged A, fragment-direct B) ---------
// A: cooperative coalesced load of x/u half-K tile, dropout+bf16 in regs,
//    staged to sA (17.4 KB LDS only -> 6-8 blocks/CU resident; inter-block
//    TLP hides each block's barrier drain).
// B: read per-MFMA directly from wF (fragment-ordered, 64 KB, L1/L2-hot):
//    one coalesced 1 KB wave-load per (kh,k0,tt), no sB, no sB barrier.
__global__ __launch_bounds__(256, 6) void gemm_kernel(const float* __restrict__ x,
                                                      const float* __restrict__ u,
                                                      const unsigned short* __restrict__ wF,
                                                      unsigned short* __restrict__ xw) {
    __shared__ unsigned short sA[64 * 136];
    int t = threadIdx.x;
    int wave = t >> 6, lane = t & 63;
    int n = lane & 15, q = lane >> 4;
    int m0 = blockIdx.x * 64;

    float4v acc[8];
#pragma unroll
    for (int i = 0; i < 8; i++) acc[i] = {0.f, 0.f, 0.f, 0.f};

    for (int kh = 0; kh < 2; kh++) {
#pragma unroll
        for (int i = 0; i < 8; i++) {
            int idx = t + i * 256;
            int row = idx >> 5;
            int c4 = idx & 31;
            const float* xp = x + (size_t)(m0 + row) * Ff + kh * 128 + c4 * 4;
            const float* up = u + (size_t)(m0 + row) * Ff + kh * 128 + c4 * 4;
            float4 xv = *(const float4*)xp;
            float4 uv = *(const float4*)up;
            ushort4v a;
            a.x = f2b(uv.x > 0.5f ? xv.x * 2.0f : 0.0f);
            a.y = f2b(uv.y > 0.5f ? xv.y * 2.0f : 0.0f);
            a.z = f2b(uv.z > 0.5f ? xv.z * 2.0f : 0.0f);
            a.w = f2b(uv.w > 0.5f ? xv.w * 2.0f : 0.0f);
            *(ushort4v*)(&sA[row * 136 + c4 * 4]) = a;
        }
        __syncthreads();
#pragma unroll
        for (int k0 = 0; k0 < 128; k0 += 32) {
            short8 af = *(const short8*)(&sA[(wave * 16 + n) * 136 + k0 + q * 8]);
            const unsigned short* wfb = wF + (size_t)(kh * 4 + (k0 >> 5)) * 4096 + lane * 8;
#pragma unroll
            for (int tt = 0; tt < 8; tt++) {
                short8 bf = *(const short8*)(wfb + tt * 512);
                acc[tt] = __builtin_amdgcn_mfma_f32_16x16x32_bf16(af, bf, acc[tt], 0, 0, 0);
            }
        }
        __syncthreads();
    }
#pragma unroll
    for (int tt = 0; tt < 8; tt++) {
#pragma unroll
        for (int r = 0; r < 4; r++) {
            int orow = m0 + wave * 16 + q * 4 + r;
            int col = tt * 16 + n;
            xw[(size_t)orow * Hh + col] = f2b(acc[tt][r]);
        }
    }
}

// ---------------- K3: SpMM — LDS row-sort + broadcast-read MLP ---------------
// Phases 1-3 (cheap): histogram 64 rows, scan, scatter into row-sorted ssort.
// Phase 4: per row, wave walks edges via wave-uniform ds_read_b64 broadcast:
// 1 v_add (pre-masked col byte offset) + 1 dword gather (L2, XCD-local) +
// 2 unpack + 2 fma per edge.
__global__ __launch_bounds__(256) void spmm_kernel(const int* __restrict__ cur,
                                                   const int2* __restrict__ bkt,
                                                   const unsigned short* __restrict__ xw,
                                                   float* __restrict__ out) {
    __shared__ int2 ssort[CAP];       // 20.5 KB sorted edges
    __shared__ int rh[CHUNK];
    __shared__ int roff[CHUNK];
    __shared__ int rcur[CHUNK];
    int raw = blockIdx.x;
    int blk = (raw & 7) * NCH + (raw >> 3);   // batch b -> XCD b
    int b = blk / NCH, ch = blk % NCH;
    int t = threadIdx.x, w = t >> 6, lane = t & 63;

    if (t < CHUNK) rh[t] = 0;
    __syncthreads();
    int cnt = cur[blk];
    if (cnt > CAP) cnt = CAP;
    const int2* pe = bkt + (size_t)blk * CAP;

    for (int i = t; i < cnt; i += 256)
        atomicAdd(&rh[((unsigned)pe[i].x) >> 26], 1);
    __syncthreads();
    if (w == 0) {
        int v = rh[lane];
        int s = v;
#pragma unroll
        for (int d = 1; d < 64; d <<= 1) {
            int o = __shfl_up(s, d);
            if (lane >= d) s += o;
        }
        roff[lane] = s - v;
        rcur[lane] = s - v;
    }
    __syncthreads();
    for (int i = t; i < cnt; i += 256) {
        int2 e = pe[i];
        int p = atomicAdd(&rcur[((unsigned)e.x) >> 26], 1);
        ssort[p] = make_int2(e.x & 0x3FFF00, e.y);   // col byte-offset only
    }
    __syncthreads();

    const char* xwb = (const char*)(xw + (size_t)b * Nn * Hh);
    int lane4 = lane * 4;
    for (int rr = 0; rr < 16; rr++) {
        int rl = w * 16 + rr;
        int r = ch * CHUNK + rl;
        if (r >= Nn) break;
        int off = roff[rl];
        int rcnt = rh[rl];

        float a0[4], a1[4];
#pragma unroll
        for (int k = 0; k < 4; k++) { a0[k] = 0.f; a1[k] = 0.f; }

        int mn = rcnt & ~3;
        for (int i = 0; i < mn; i += 4) {
#pragma unroll
            for (int k = 0; k < 4; k++) {
                int2 e = ssort[off + i + k];
                unsigned int two = *(const unsigned int*)(xwb + (unsigned)(e.x + lane4));
                float v = i2f(e.y);
                a0[k] += v * lo_bf(two);
                a1[k] += v * hi_bf(two);
            }
        }
        for (int i = mn; i < rcnt; i++) {
            int2 e = ssort[off + i];
            unsigned int two = *(const unsigned int*)(xwb + (unsigned)(e.x + lane4));
            float v = i2f(e.y);
            a0[i - mn] += v * lo_bf(two);
            a1[i - mn] += v * hi_bf(two);
        }
        float s0 = (a0[0] + a0[1]) + (a0[2] + a0[3]);
        float s1 = (a1[0] + a1[1]) + (a1[2] + a1[3]);
        float2 res;
        res.x = s0;
        res.y = s1;
        *(float2*)(out + ((size_t)b * Nn + r) * Hh + lane * 2) = res;
    }
}

extern "C" void kernel_launch(void* const* d_in, const int* in_sizes, int n_in,
                              void* d_out, int out_size, void* d_ws, size_t ws_size,
                              hipStream_t stream) {
    const float* x    = (const float*)d_in[0]; // fp32 [B,N,F]
    const float* du   = (const float*)d_in[1]; // fp32 [B,N,F]
    const int*   rows = (const int*)d_in[2];   // int32 [B,E]
    const int*   cols = (const int*)d_in[3];   // int32 [B,E]
    const float* vals = (const float*)d_in[4]; // fp32 [B,E]
    const float* w    = (const float*)d_in[5]; // fp32 [F,H]
    float*       out  = (float*)d_out;         // fp32 [B,N,H]

    char* p = (char*)d_ws;
    unsigned short* xw = (unsigned short*)p; p += (size_t)Mm * Hh * 2;   // 20.48 MB
    unsigned short* wF = (unsigned short*)p; p += (size_t)Ff * Hh * 2;   // 64 KB
    int* cur   = (int*)p; p += (size_t)Bb * NCH * 4;                     // 5 KB
    int2* bkt  = (int2*)p; p += (size_t)Bb * NCH * CAP * 8;              // 25.7 MB

    hipMemsetAsync(cur, 0, (size_t)Bb * NCH * 4, stream);
    bucket2_kernel<<<Bb * GPB + TW_BLOCKS, 256, 0, stream>>>(rows, cols, vals, cur, bkt, w, wF);
    gemm_kernel<<<Mm / 64, 256, 0, stream>>>(x, du, wF, xw);
    spmm_kernel<<<Bb * NCH, 256, 0, stream>>>(cur, bkt, xw, out);
}

// Round 6
// 278.499 us; speedup vs baseline: 1.0608x; 1.0608x over previous
//
#include <hip/hip_runtime.h>
#include <hip/hip_bf16.h>

#define DEVINL __device__ __forceinline__

constexpr int Bb = 8;
constexpr int Nn = 10000;
constexpr int Ff = 256;     // F (K dim of GEMM)
constexpr int Hh = 128;     // H (N dim of GEMM)
constexpr int Ee = 320000;
constexpr int Mm = Bb * Nn; // 80000 GEMM rows

constexpr int CHUNK = 64;                     // rows per bucket
constexpr int NCH = (Nn + CHUNK - 1) / CHUNK; // 157 buckets/batch
constexpr int CAP = 2560;                     // bucket capacity (mean 2048, 11 sigma)
constexpr int GPB = 80;                       // binning workgroups per batch
constexpr int EPG = Ee / GPB;                 // 4000 edges per workgroup
constexpr int BUCKET_BLOCKS = Bb * GPB;       // 640
constexpr int GEMM_BLOCKS = Mm / 64;          // 1250
// dynamic LDS: max(bucket: 32000+4*628+16=34528, gemm: 17408) -> 34560
constexpr int DYN_LDS = 34560;

typedef __attribute__((ext_vector_type(8))) short short8;
typedef __attribute__((ext_vector_type(4))) float float4v;
typedef __attribute__((ext_vector_type(4))) unsigned short ushort4v;

DEVINL unsigned short f2b(float f) {
    unsigned int u;
    __builtin_memcpy(&u, &f, 4);
    unsigned int r = (u + 0x7fffu + ((u >> 16) & 1u)) >> 16;
    return (unsigned short)r;
}
DEVINL float i2f(int i) {
    float f;
    __builtin_memcpy(&f, &i, 4);
    return f;
}
DEVINL float lo_bf(unsigned int two) {
    unsigned int u = two << 16;
    float f;
    __builtin_memcpy(&f, &u, 4);
    return f;
}
DEVINL float hi_bf(unsigned int two) {
    unsigned int u = two & 0xffff0000u;
    float f;
    __builtin_memcpy(&f, &u, 4);
    return f;
}

// ---------------- K0: pack W into MFMA-B-fragment order (tiny, ~3 us) --------
//   wF[ksl*4096 + tt*512 + lane*8 + j] = bf16(w[(ksl*32 + (lane>>4)*8 + j)*H
//                                               + tt*16 + (lane&15)])
__global__ __launch_bounds__(256) void pack_kernel(const float* __restrict__ w,
                                                   unsigned short* __restrict__ wF) {
    int idx = blockIdx.x * 256 + threadIdx.x;
    if (idx < Ff * Hh) {
        int j = idx & 7;
        int lane = (idx >> 3) & 63;
        int tt = (idx >> 9) & 7;
        int ksl = idx >> 12;
        int k = ksl * 32 + (lane >> 4) * 8 + j;
        int h = tt * 16 + (lane & 15);
        wF[idx] = f2b(w[(size_t)k * Hh + h]);
    }
}

// ---------------- K1: FUSED bucket-binning + dropout-GEMM --------------------
// bucket2 (scattered atomics, ~1% VALU) and gemm (streaming reads, idle pipes)
// have no data dependency — co-residency overlaps their latencies instead of
// serializing two ~70 us latency-bound dispatches.
// blocks [0, 640):   LDS-staged bucket sort, contiguous run writes.
//                    XCD swizzle: b = raw&7 keeps batch b's cur/bkt on XCD b.
// blocks [640, 1890): dropout+GEMM, staged A (dyn LDS), fragment-direct B (wF).
__global__ __launch_bounds__(256, 4) void fused_kernel(const int* __restrict__ rows,
                                                       const int* __restrict__ cols,
                                                       const float* __restrict__ vals,
                                                       int* __restrict__ cur,
                                                       int2* __restrict__ bkt,
                                                       const float* __restrict__ x,
                                                       const float* __restrict__ u,
                                                       const unsigned short* __restrict__ wF,
                                                       unsigned short* __restrict__ xw) {
    extern __shared__ char dyn[];
    int t = threadIdx.x;

    if (blockIdx.x < BUCKET_BLOCKS) {
        // -------- bucket branch --------
        int2* sedge = (int2*)dyn;                        // 32000 B
        int* lcnt = (int*)(dyn + EPG * 8);               // +628
        int* lofs = lcnt + NCH;
        int* lcur = lofs + NCH;
        int* gall = lcur + NCH;
        int* wsum = gall + NCH;                          // 4 ints
        int raw = blockIdx.x;
        int b = raw & 7;
        int g = raw >> 3;
        const int base = b * Ee + g * EPG;

        for (int j = t; j < NCH; j += 256) lcnt[j] = 0;
        __syncthreads();
        for (int i = t; i < EPG; i += 256)
            atomicAdd(&lcnt[rows[base + i] >> 6], 1);
        __syncthreads();
        {   // exclusive scan over 157 buckets
            int lane = t & 63, wv = t >> 6;
            int v = (t < NCH) ? lcnt[t] : 0;
            int incl = v;
#pragma unroll
            for (int d = 1; d < 64; d <<= 1) {
                int o = __shfl_up(incl, d);
                if (lane >= d) incl += o;
            }
            if (lane == 63) wsum[wv] = incl;
            __syncthreads();
            if (t == 0) {
                int s = 0;
#pragma unroll
                for (int k = 0; k < 4; k++) { int xx = wsum[k]; wsum[k] = s; s += xx; }
            }
            __syncthreads();
            if (t < NCH) {
                int ex = incl - v + wsum[wv];
                lofs[t] = ex;
                lcur[t] = ex;
            }
        }
        __syncthreads();
        for (int j = t; j < NCH; j += 256) {
            int gb = atomicAdd(&cur[b * NCH + j], lcnt[j]);
            gall[j] = gb - lofs[j];
        }
        __syncthreads();
        for (int i = t; i < EPG; i += 256) {
            int r = rows[base + i];
            int c = cols[base + i];
            float vf = vals[base + i];
            int vb;
            __builtin_memcpy(&vb, &vf, 4);
            int bk = r >> 6;
            int p = atomicAdd(&lcur[bk], 1);
            sedge[p] = make_int2(((r & 63) << 26) | (c << 8) | bk, vb);
        }
        __syncthreads();
        for (int i = t; i < EPG; i += 256) {
            int2 e = sedge[i];
            int j = e.x & 0xff;
            int slot = gall[j] + i;
            if (slot < CAP)
                bkt[(size_t)(b * NCH + j) * CAP + slot] = e;
        }
        return;
    }

    // -------- gemm branch --------
    unsigned short* sA = (unsigned short*)dyn;           // 64*136*2 = 17408 B
    int wave = t >> 6, lane = t & 63;
    int n = lane & 15, q = lane >> 4;
    int m0 = (blockIdx.x - BUCKET_BLOCKS) * 64;

    float4v acc[8];
#pragma unroll
    for (int i = 0; i < 8; i++) acc[i] = {0.f, 0.f, 0.f, 0.f};

    for (int kh = 0; kh < 2; kh++) {
#pragma unroll
        for (int i = 0; i < 8; i++) {
            int idx = t + i * 256;
            int row = idx >> 5;
            int c4 = idx & 31;
            const float* xp = x + (size_t)(m0 + row) * Ff + kh * 128 + c4 * 4;
            const float* up = u + (size_t)(m0 + row) * Ff + kh * 128 + c4 * 4;
            float4 xv = *(const float4*)xp;
            float4 uv = *(const float4*)up;
            ushort4v a;
            a.x = f2b(uv.x > 0.5f ? xv.x * 2.0f : 0.0f);
            a.y = f2b(uv.y > 0.5f ? xv.y * 2.0f : 0.0f);
            a.z = f2b(uv.z > 0.5f ? xv.z * 2.0f : 0.0f);
            a.w = f2b(uv.w > 0.5f ? xv.w * 2.0f : 0.0f);
            *(ushort4v*)(&sA[row * 136 + c4 * 4]) = a;
        }
        __syncthreads();
#pragma unroll
        for (int k0 = 0; k0 < 128; k0 += 32) {
            short8 af = *(const short8*)(&sA[(wave * 16 + n) * 136 + k0 + q * 8]);
            const unsigned short* wfb = wF + (size_t)(kh * 4 + (k0 >> 5)) * 4096 + lane * 8;
#pragma unroll
            for (int tt = 0; tt < 8; tt++) {
                short8 bf = *(const short8*)(wfb + tt * 512);
                acc[tt] = __builtin_amdgcn_mfma_f32_16x16x32_bf16(af, bf, acc[tt], 0, 0, 0);
            }
        }
        __syncthreads();
    }
#pragma unroll
    for (int tt = 0; tt < 8; tt++) {
#pragma unroll
        for (int r = 0; r < 4; r++) {
            int orow = m0 + wave * 16 + q * 4 + r;
            int col = tt * 16 + n;
            xw[(size_t)orow * Hh + col] = f2b(acc[tt][r]);
        }
    }
}

// ---------------- K3: SpMM — LDS row-sort + broadcast-read MLP ---------------
__global__ __launch_bounds__(256) void spmm_kernel(const int* __restrict__ cur,
                                                   const int2* __restrict__ bkt,
                                                   const unsigned short* __restrict__ xw,
                                                   float* __restrict__ out) {
    __shared__ int2 ssort[CAP];       // 20.5 KB sorted edges
    __shared__ int rh[CHUNK];
    __shared__ int roff[CHUNK];
    __shared__ int rcur[CHUNK];
    int raw = blockIdx.x;
    int blk = (raw & 7) * NCH + (raw >> 3);   // batch b -> XCD b
    int b = blk / NCH, ch = blk % NCH;
    int t = threadIdx.x, w = t >> 6, lane = t & 63;

    if (t < CHUNK) rh[t] = 0;
    __syncthreads();
    int cnt = cur[blk];
    if (cnt > CAP) cnt = CAP;
    const int2* pe = bkt + (size_t)blk * CAP;

    for (int i = t; i < cnt; i += 256)
        atomicAdd(&rh[((unsigned)pe[i].x) >> 26], 1);
    __syncthreads();
    if (w == 0) {
        int v = rh[lane];
        int s = v;
#pragma unroll
        for (int d = 1; d < 64; d <<= 1) {
            int o = __shfl_up(s, d);
            if (lane >= d) s += o;
        }
        roff[lane] = s - v;
        rcur[lane] = s - v;
    }
    __syncthreads();
    for (int i = t; i < cnt; i += 256) {
        int2 e = pe[i];
        int p = atomicAdd(&rcur[((unsigned)e.x) >> 26], 1);
        ssort[p] = make_int2(e.x & 0x3FFF00, e.y);   // col byte-offset only
    }
    __syncthreads();

    const char* xwb = (const char*)(xw + (size_t)b * Nn * Hh);
    int lane4 = lane * 4;
    for (int rr = 0; rr < 16; rr++) {
        int rl = w * 16 + rr;
        int r = ch * CHUNK + rl;
        if (r >= Nn) break;
        int off = roff[rl];
        int rcnt = rh[rl];

        float a0[4], a1[4];
#pragma unroll
        for (int k = 0; k < 4; k++) { a0[k] = 0.f; a1[k] = 0.f; }

        int mn = rcnt & ~3;
        for (int i = 0; i < mn; i += 4) {
#pragma unroll
            for (int k = 0; k < 4; k++) {
                int2 e = ssort[off + i + k];
                unsigned int two = *(const unsigned int*)(xwb + (unsigned)(e.x + lane4));
                float v = i2f(e.y);
                a0[k] += v * lo_bf(two);
                a1[k] += v * hi_bf(two);
            }
        }
        for (int i = mn; i < rcnt; i++) {
            int2 e = ssort[off + i];
            unsigned int two = *(const unsigned int*)(xwb + (unsigned)(e.x + lane4));
            float v = i2f(e.y);
            a0[i - mn] += v * lo_bf(two);
            a1[i - mn] += v * hi_bf(two);
        }
        float s0 = (a0[0] + a0[1]) + (a0[2] + a0[3]);
        float s1 = (a1[0] + a1[1]) + (a1[2] + a1[3]);
        float2 res;
        res.x = s0;
        res.y = s1;
        *(float2*)(out + ((size_t)b * Nn + r) * Hh + lane * 2) = res;
    }
}

extern "C" void kernel_launch(void* const* d_in, const int* in_sizes, int n_in,
                              void* d_out, int out_size, void* d_ws, size_t ws_size,
                              hipStream_t stream) {
    const float* x    = (const float*)d_in[0]; // fp32 [B,N,F]
    const float* du   = (const float*)d_in[1]; // fp32 [B,N,F]
    const int*   rows = (const int*)d_in[2];   // int32 [B,E]
    const int*   cols = (const int*)d_in[3];   // int32 [B,E]
    const float* vals = (const float*)d_in[4]; // fp32 [B,E]
    const float* w    = (const float*)d_in[5]; // fp32 [F,H]
    float*       out  = (float*)d_out;         // fp32 [B,N,H]

    char* p = (char*)d_ws;
    unsigned short* xw = (unsigned short*)p; p += (size_t)Mm * Hh * 2;   // 20.48 MB
    unsigned short* wF = (unsigned short*)p; p += (size_t)Ff * Hh * 2;   // 64 KB
    int* cur   = (int*)p; p += (size_t)Bb * NCH * 4;                     // 5 KB
    int2* bkt  = (int2*)p; p += (size_t)Bb * NCH * CAP * 8;              // 25.7 MB

    hipMemsetAsync(cur, 0, (size_t)Bb * NCH * 4, stream);
    pack_kernel<<<(Ff * Hh + 255) / 256, 256, 0, stream>>>(w, wF);
    fused_kernel<<<BUCKET_BLOCKS + GEMM_BLOCKS, 256, DYN_LDS, stream>>>(
        rows, cols, vals, cur, bkt, x, du, wF, xw);
    spmm_kernel<<<Bb * NCH, 256, 0, stream>>>(cur, bkt, xw, out);
}